// Round 6
// baseline (2039.792 us; speedup 1.0000x reference)
//
#include <hip/hip_runtime.h>
#include <hip/hip_bf16.h>
#include <stdint.h>

typedef __attribute__((ext_vector_type(8))) short bf16x8;
typedef __attribute__((ext_vector_type(4))) float f32x4;
typedef __attribute__((ext_vector_type(4))) unsigned int u32x4;

__device__ __forceinline__ unsigned short f2bf(float f) {
  union { float f; unsigned int u; } c; c.f = f;
  unsigned int u = c.u;
  u += 0x7FFFu + ((u >> 16) & 1u);   // round-to-nearest-even
  return (unsigned short)(u >> 16);
}
__device__ __forceinline__ float bf2f(unsigned short b) {
  union { unsigned int u; float f; } c; c.u = ((unsigned int)b) << 16;
  return c.f;
}
__device__ __forceinline__ void unpack8(const u32x4& v, float* f) {
  f[0] = bf2f((unsigned short)(v[0] & 0xFFFF)); f[1] = bf2f((unsigned short)(v[0] >> 16));
  f[2] = bf2f((unsigned short)(v[1] & 0xFFFF)); f[3] = bf2f((unsigned short)(v[1] >> 16));
  f[4] = bf2f((unsigned short)(v[2] & 0xFFFF)); f[5] = bf2f((unsigned short)(v[2] >> 16));
  f[6] = bf2f((unsigned short)(v[3] & 0xFFFF)); f[7] = bf2f((unsigned short)(v[3] >> 16));
}
// find g in [0,63] with rp[g] <= e < rp[g+1]; rp monotone, rp[0] <= e < rp[64]
__device__ __forceinline__ int bsearch64(const int* rp, int e) {
  int lo = 0, hi = 63;
  #pragma unroll
  for (int s = 0; s < 6; ++s) {
    int mid = (lo + hi + 1) >> 1;
    if (rp[mid] <= e) lo = mid; else hi = mid - 1;
  }
  return lo;
}

// ---- convert two fp32 arrays to bf16 (blockIdx.y selects which) ----
__global__ void cvt_x(const float* __restrict__ a, const float* __restrict__ b,
                      unsigned short* __restrict__ oa, unsigned short* __restrict__ ob, int n) {
  const float* src = blockIdx.y ? b : a;
  unsigned short* dst = blockIdx.y ? ob : oa;
  int i = (blockIdx.x * 256 + threadIdx.x) * 8;
  if (i >= n) return;
  float4 v0 = *(const float4*)(src + i);
  float4 v1 = *(const float4*)(src + i + 4);
  u32x4 o;
  o[0] = (unsigned int)f2bf(v0.x) | ((unsigned int)f2bf(v0.y) << 16);
  o[1] = (unsigned int)f2bf(v0.z) | ((unsigned int)f2bf(v0.w) << 16);
  o[2] = (unsigned int)f2bf(v1.x) | ((unsigned int)f2bf(v1.y) << 16);
  o[3] = (unsigned int)f2bf(v1.z) | ((unsigned int)f2bf(v1.w) << 16);
  *(u32x4*)(dst + i) = o;
}

struct WPtrs { const float* p[8]; };

// ---- convert the 8 [128x128] weight matrices to bf16 ----
__global__ void cvt_w(WPtrs w, unsigned short* __restrict__ out) {
  int wi = blockIdx.y;
  int i = (blockIdx.x * 256 + threadIdx.x) * 8;
  const float* src = w.p[wi];
  float4 v0 = *(const float4*)(src + i);
  float4 v1 = *(const float4*)(src + i + 4);
  u32x4 o;
  o[0] = (unsigned int)f2bf(v0.x) | ((unsigned int)f2bf(v0.y) << 16);
  o[1] = (unsigned int)f2bf(v0.z) | ((unsigned int)f2bf(v0.w) << 16);
  o[2] = (unsigned int)f2bf(v1.x) | ((unsigned int)f2bf(v1.y) << 16);
  o[3] = (unsigned int)f2bf(v1.z) | ((unsigned int)f2bf(v1.w) << 16);
  *(u32x4*)(out + wi * 16384 + i) = o;
}

// ---- counting-sort pipeline, both relations per launch (blockIdx.y) ----
// hist/reorder: 4 edges per thread (int4 loads) -> 4 independent atomic chains
__global__ void hist2_k(const int* __restrict__ ei0, const int* __restrict__ ei1,
                        int* __restrict__ cnt, int E, int N) {
  const int* ei = blockIdx.y ? ei1 : ei0;
  int* c = cnt + blockIdx.y * N;
  int e = (blockIdx.x * 256 + threadIdx.x) * 4;
  if (e >= E) return;
  if (e + 4 <= E) {
    int4 d4 = *(const int4*)(ei + E + e);
    atomicAdd(&c[d4.x], 1); atomicAdd(&c[d4.y], 1);
    atomicAdd(&c[d4.z], 1); atomicAdd(&c[d4.w], 1);
  } else {
    for (int k = 0; k < 4 && e + k < E; ++k) atomicAdd(&c[ei[E + e + k]], 1);
  }
}

__global__ void scan_a2(const int* __restrict__ cnt, int* __restrict__ incl,
                        int* __restrict__ bsum, int n) {
  const int* in = cnt + blockIdx.y * n;
  int* out = incl + blockIdx.y * n;
  int* bs = bsum + blockIdx.y * 128;
  __shared__ int sm[1024];
  int i = blockIdx.x * 1024 + threadIdx.x;
  int v = (i < n) ? in[i] : 0;
  sm[threadIdx.x] = v;
  __syncthreads();
  for (int off = 1; off < 1024; off <<= 1) {
    int t = (threadIdx.x >= off) ? sm[threadIdx.x - off] : 0;
    __syncthreads();
    sm[threadIdx.x] += t;
    __syncthreads();
  }
  if (i < n) out[i] = sm[threadIdx.x];
  if (threadIdx.x == 1023) bs[blockIdx.x] = sm[1023];
}

__global__ void scan_b2(int* __restrict__ bsum, int nb) {
  int* bs = bsum + blockIdx.y * 128;
  __shared__ int sm[128];
  int t = threadIdx.x;
  int v = (t < nb) ? bs[t] : 0;
  sm[t] = v;
  __syncthreads();
  for (int off = 1; off < 128; off <<= 1) {
    int u = (t >= off) ? sm[t - off] : 0;
    __syncthreads();
    sm[t] += u;
    __syncthreads();
  }
  if (t < nb) bs[t] = sm[t] - v;   // exclusive block offsets
}

__global__ void scan_c2(const int* __restrict__ cnt, const int* __restrict__ incl,
                        const int* __restrict__ bsum, int* __restrict__ rowptr,
                        int* __restrict__ cursor, int n) {
  int y = blockIdx.y;
  int i = blockIdx.x * 256 + threadIdx.x;
  if (i >= n) return;
  int e = incl[y * n + i] - cnt[y * n + i] + bsum[y * 128 + (i >> 10)];
  rowptr[y * n + i] = e;
  cursor[y * n + i] = e;
}

__global__ void reorder2_k(const int* __restrict__ ei0, const int* __restrict__ ei1,
                           int* __restrict__ cursor, int* __restrict__ ssrc, int E, int N) {
  const int* ei = blockIdx.y ? ei1 : ei0;
  int* cur = cursor + blockIdx.y * N;
  int* ss = ssrc + blockIdx.y * E;
  int e = (blockIdx.x * 256 + threadIdx.x) * 4;
  if (e >= E) return;
  if (e + 4 <= E) {
    int4 s4 = *(const int4*)(ei + e);
    int4 d4 = *(const int4*)(ei + E + e);
    int p0 = atomicAdd(&cur[d4.x], 1);
    int p1 = atomicAdd(&cur[d4.y], 1);
    int p2 = atomicAdd(&cur[d4.z], 1);
    int p3 = atomicAdd(&cur[d4.w], 1);
    ss[p0] = s4.x; ss[p1] = s4.y; ss[p2] = s4.z; ss[p3] = s4.w;
  } else {
    for (int k = 0; k < 4 && e + k < E; ++k) {
      int s = ei[e + k], d = ei[E + e + k];
      ss[atomicAdd(&cur[d], 1)] = s;
    }
  }
}

// ---- fused gather-mean + dual matmul ----
// out = mean_csr(xsrc) @ Wl^T + xdst @ Wr^T + bias (+relu->bf16 | ->f32)
// Gather is EDGE-PARALLEL (round-5 lesson: node-parallel serializes deg~6
// dependent loads): tile's CSR edge range is contiguous; 16-lane groups take
// 2 edges/iter, binary-search local dst in cached rowptr[65], accumulate via
// LDS f32 atomicAdd with (sub+j)&7 bank rotation (~2-way, free per m136).
// LDS (34816B) is phase-aliased: f32 acc -> bf16 A-tile + xdst tile -> epilogue.
struct FusedArgs {
  const unsigned short* xsrc; const unsigned short* xdst;
  const int* rowptr; const int* ssrc;
  const unsigned short* Wl; const unsigned short* Wr;
  const float* bias; void* out;
};

template<int RELU_BF16>
__global__ __launch_bounds__(256, 3) void fused_k(FusedArgs f0, FusedArgs f1, int n, int Etot) {
  FusedArgs A = blockIdx.y ? f1 : f0;
  __shared__ __align__(16) float lds_f[8704];    // 34816 B, aliased across phases
  __shared__ int lds_rp[65];
  unsigned short* lds = (unsigned short*)lds_f;
  int n0 = blockIdx.x * 64;
  int tid = threadIdx.x;
  int wave = tid >> 6, lane = tid & 63;
  int lr = lane & 15;             // A row-in-16 / B col-in-16
  int kb = (lane >> 4) * 8;       // k sub-offset within the 32-wide K step

  // ---- init: rowptr cache, zero acc, issue W preload (latency hides under gather) ----
  if (tid < 65) {
    int idx = n0 + tid;
    lds_rp[tid] = (idx < n) ? A.rowptr[idx] : Etot;
  }
  #pragma unroll
  for (int i = 0; i < 9; ++i) {
    int j = i * 256 + tid;
    if (j < 2176) *(f32x4*)(lds_f + j * 4) = (f32x4){0.f, 0.f, 0.f, 0.f};
  }
  const unsigned short* Wg[2] = { A.Wl, A.Wr };
  bf16x8 breg[2][2][4];
  #pragma unroll
  for (int h = 0; h < 2; ++h) {
    const unsigned short* wb = Wg[h] + (size_t)(wave * 32 + lr) * 128 + kb;
    #pragma unroll
    for (int jt = 0; jt < 2; ++jt)
      #pragma unroll
      for (int ks = 0; ks < 4; ++ks)
        breg[h][jt][ks] = *(const bf16x8*)(wb + jt * 16 * 128 + ks * 32);
  }
  __syncthreads();

  // ---- phase 1: edge-parallel gather-accumulate into f32 acc (stride 136) ----
  {
    int grp = tid >> 4;           // 16 groups of 16 lanes; group handles 2 edges/iter
    int sub = tid & 15;
    int rbeg = lds_rp[0], rend = lds_rp[64];
    for (int base = rbeg; base < rend; base += 32) {
      int e0 = base + grp * 2, e1 = e0 + 1;
      bool v0 = e0 < rend, v1 = e1 < rend;
      int i0 = v0 ? A.ssrc[e0] : 0;
      int i1 = v1 ? A.ssrc[e1] : 0;
      u32x4 r0 = {0u,0u,0u,0u}, r1 = {0u,0u,0u,0u};
      if (v0) r0 = *(const u32x4*)(A.xsrc + (size_t)i0 * 128 + sub * 8);
      if (v1) r1 = *(const u32x4*)(A.xsrc + (size_t)i1 * 128 + sub * 8);
      if (v0) {
        int g = bsearch64(lds_rp, e0);
        float fv[8]; unpack8(r0, fv);
        float* drow = lds_f + g * 136 + sub * 8;
        #pragma unroll
        for (int j = 0; j < 8; ++j) { int jj = (sub + j) & 7; atomicAdd(&drow[jj], fv[jj]); }
      }
      if (v1) {
        int g = bsearch64(lds_rp, e1);
        float fv[8]; unpack8(r1, fv);
        float* drow = lds_f + g * 136 + sub * 8;
        #pragma unroll
        for (int j = 0; j < 8; ++j) { int jj = (sub + j) & 7; atomicAdd(&drow[jj], fv[jj]); }
      }
    }
  }
  __syncthreads();

  // ---- phase 2: acc -> regs (mean), issue xdst loads; then overlay-write tiles ----
  int cr = tid >> 2;                 // row 0..63
  int cq = (tid & 3) * 32;           // col 0..96 step 32
  float inv;
  {
    int deg = lds_rp[cr + 1] - lds_rp[cr];
    inv = deg > 0 ? 1.0f / (float)deg : 0.0f;
  }
  f32x4 mv[8];
  #pragma unroll
  for (int i = 0; i < 8; ++i) mv[i] = *(const f32x4*)(lds_f + cr * 136 + cq + i * 4);
  u32x4 xv[4];
  #pragma unroll
  for (int it = 0; it < 4; ++it) {
    int li = (it * 256 + tid) * 8;
    int r = li >> 7, c = li & 127;
    xv[it] = (u32x4){0u,0u,0u,0u};
    if (n0 + r < n) xv[it] = *(const u32x4*)(A.xdst + (size_t)(n0 + r) * 128 + c);
  }
  __syncthreads();                   // all acc reads done; safe to overlay
  #pragma unroll
  for (int i = 0; i < 4; ++i) {
    u32x4 o;
    o[0] = (unsigned int)f2bf(mv[2*i][0]*inv)   | ((unsigned int)f2bf(mv[2*i][1]*inv) << 16);
    o[1] = (unsigned int)f2bf(mv[2*i][2]*inv)   | ((unsigned int)f2bf(mv[2*i][3]*inv) << 16);
    o[2] = (unsigned int)f2bf(mv[2*i+1][0]*inv) | ((unsigned int)f2bf(mv[2*i+1][1]*inv) << 16);
    o[3] = (unsigned int)f2bf(mv[2*i+1][2]*inv) | ((unsigned int)f2bf(mv[2*i+1][3]*inv) << 16);
    *(u32x4*)(lds + cr * 136 + cq + i * 8) = o;
  }
  {
    unsigned short* dstl = lds + 8704;   // xdst tile, stride 136
    #pragma unroll
    for (int it = 0; it < 4; ++it) {
      int li = (it * 256 + tid) * 8;
      int r = li >> 7, c = li & 127;
      *(u32x4*)(dstl + r * 136 + c) = xv[it];
    }
  }
  __syncthreads();

  // ---- phase 3: pure LDS + register MFMA loop: 32 ds_read_b128, 64 MFMA ----
  f32x4 acc[4][2] = {};           // [row tile][col tile], statically indexed
  #pragma unroll
  for (int h = 0; h < 2; ++h) {
    const unsigned short* Abase = lds + h * 8704 + lr * 136 + kb;
    #pragma unroll
    for (int rt = 0; rt < 4; ++rt) {
      #pragma unroll
      for (int ks = 0; ks < 4; ++ks) {
        bf16x8 a = *(const bf16x8*)(Abase + rt * 16 * 136 + ks * 32);
        acc[rt][0] = __builtin_amdgcn_mfma_f32_16x16x32_bf16(a, breg[h][0][ks], acc[rt][0], 0, 0, 0);
        acc[rt][1] = __builtin_amdgcn_mfma_f32_16x16x32_bf16(a, breg[h][1][ks], acc[rt][1], 0, 0, 0);
      }
    }
  }

  // ---- epilogue: acc -> LDS (overlay) -> coalesced full-row global stores ----
  // C/D layout: col = lane&15, row = (lane>>4)*4 + reg  [verified m89/m91]
  __syncthreads();                // all A-tile reads done; safe to overlay lds
  if (RELU_BF16) {
    unsigned short* st = (unsigned short*)lds;   // 64 x 128, stride 136
    #pragma unroll
    for (int jt = 0; jt < 2; ++jt) {
      int col = wave * 32 + jt * 16 + lr;
      float bv = A.bias[col];
      #pragma unroll
      for (int rt = 0; rt < 4; ++rt) {
        int rloc = rt * 16 + (lane >> 4) * 4;
        #pragma unroll
        for (int i = 0; i < 4; ++i) {
          float v = acc[rt][jt][i] + bv;
          v = v > 0.f ? v : 0.f;
          st[(rloc + i) * 136 + col] = f2bf(v);
        }
      }
    }
    __syncthreads();
    #pragma unroll
    for (int it = 0; it < 4; ++it) {
      int flat = (it * 256 + tid) * 8;
      int r = flat >> 7, c = flat & 127;
      if (n0 + r < n) {
        u32x4 v = *(const u32x4*)(st + r * 136 + c);
        *(u32x4*)((unsigned short*)A.out + (size_t)(n0 + r) * 128 + c) = v;
      }
    }
  } else {
    float* st = (float*)lds;                     // 64 x 128, stride 132
    #pragma unroll
    for (int jt = 0; jt < 2; ++jt) {
      int col = wave * 32 + jt * 16 + lr;
      float bv = A.bias[col];
      #pragma unroll
      for (int rt = 0; rt < 4; ++rt) {
        int rloc = rt * 16 + (lane >> 4) * 4;
        #pragma unroll
        for (int i = 0; i < 4; ++i)
          st[(rloc + i) * 132 + col] = acc[rt][jt][i] + bv;
      }
    }
    __syncthreads();
    #pragma unroll
    for (int it = 0; it < 8; ++it) {
      int flat = (it * 256 + tid) * 4;
      int r = flat >> 7, c = flat & 127;
      if (n0 + r < n) {
        u32x4 v = *(const u32x4*)(st + r * 132 + c);
        *(u32x4*)((float*)A.out + (size_t)(n0 + r) * 128 + c) = v;
      }
    }
  }
}

extern "C" void kernel_launch(void* const* d_in, const int* in_sizes, int n_in,
                              void* d_out, int out_size, void* d_ws, size_t ws_size,
                              hipStream_t stream) {
  const float* xp = (const float*)d_in[0];
  const float* xt = (const float*)d_in[1];
  const int* ei_pt = (const int*)d_in[2];
  const int* ei_tp = (const int*)d_in[3];
  WPtrs wp;
  for (int i = 0; i < 8; ++i) wp.p[i] = (const float*)d_in[4 + i];
  const float* bl0_pt = (const float*)d_in[12];
  const float* bl0_tp = (const float*)d_in[13];
  const float* bl1_pt = (const float*)d_in[14];
  const float* bl1_tp = (const float*)d_in[15];
  float* out = (float*)d_out;     // [o_player (N*128) | o_team (N*128)]

  const int N = in_sizes[0] / 128;
  const int E = in_sizes[2] / 2;
  const size_t NB = (size_t)N * 128 * 2;    // bf16 feature matrix bytes

  char* ws = (char*)d_ws;
  size_t off = 0;
  auto alloc = [&](size_t bytes) -> void* {
    off = (off + 255) & ~(size_t)255;
    void* p = ws + off; off += bytes; return p;
  };
  unsigned short* xp_bf  = (unsigned short*)alloc(NB);
  unsigned short* xt_bf  = (unsigned short*)alloc(NB);
  unsigned short* hp_bf  = (unsigned short*)alloc(NB);
  unsigned short* ht_bf  = (unsigned short*)alloc(NB);
  unsigned short* wbf    = (unsigned short*)alloc(8 * 16384 * 2);
  int* cnt    = (int*)alloc((size_t)2 * N * 4);
  int* rowptr = (int*)alloc((size_t)2 * N * 4);
  int* cursor = (int*)alloc((size_t)2 * N * 4);
  int* incl   = (int*)alloc((size_t)2 * N * 4);
  int* ssrc   = (int*)alloc((size_t)2 * E * 4);
  int* bsum   = (int*)alloc(2 * 128 * 4);

  const int nx = N * 128;
  // fp32 -> bf16 conversions
  cvt_x<<<dim3((nx / 8 + 255) / 256, 2), 256, 0, stream>>>(xp, xt, xp_bf, xt_bf, nx);
  cvt_w<<<dim3(8, 8), 256, 0, stream>>>(wp, wbf);

  // CSR build, both relations per launch (reused by both layers)
  const int SCB = (N + 1023) / 1024;
  const int EB4 = ((E + 3) / 4 + 255) / 256;
  hipMemsetAsync(cnt, 0, (size_t)2 * N * 4, stream);
  hist2_k<<<dim3(EB4, 2), 256, 0, stream>>>(ei_pt, ei_tp, cnt, E, N);
  scan_a2<<<dim3(SCB, 2), 1024, 0, stream>>>(cnt, incl, bsum, N);
  scan_b2<<<dim3(1, 2), 128, 0, stream>>>(bsum, SCB);
  scan_c2<<<dim3((N + 255) / 256, 2), 256, 0, stream>>>(cnt, incl, bsum, rowptr, cursor, N);
  reorder2_k<<<dim3(EB4, 2), 256, 0, stream>>>(ei_pt, ei_tp, cursor, ssrc, E, N);

  const int LNB = (N + 63) / 64;
  // relation 0 = pt (dst type team), relation 1 = tp (dst type player)
  // ---- layer 0 (relu, bf16 out) ----
  FusedArgs l0a = { xp_bf, xt_bf, rowptr,     ssrc,     wbf + 0*16384, wbf + 1*16384, bl0_pt, ht_bf };
  FusedArgs l0b = { xt_bf, xp_bf, rowptr + N, ssrc + E, wbf + 2*16384, wbf + 3*16384, bl0_tp, hp_bf };
  fused_k<1><<<dim3(LNB, 2), 256, 0, stream>>>(l0a, l0b, N, E);
  // ---- layer 1 (f32 out) ----
  FusedArgs l1a = { hp_bf, ht_bf, rowptr,     ssrc,     wbf + 4*16384, wbf + 5*16384, bl1_pt, out + (size_t)N * 128 };
  FusedArgs l1b = { ht_bf, hp_bf, rowptr + N, ssrc + E, wbf + 6*16384, wbf + 7*16384, bl1_tp, out };
  fused_k<0><<<dim3(LNB, 2), 256, 0, stream>>>(l1a, l1b, N, E);
}

// Round 7
// 503.898 us; speedup vs baseline: 4.0480x; 4.0480x over previous
//
#include <hip/hip_runtime.h>
#include <hip/hip_bf16.h>
#include <stdint.h>

typedef __attribute__((ext_vector_type(8))) short bf16x8;
typedef __attribute__((ext_vector_type(4))) float f32x4;
typedef __attribute__((ext_vector_type(4))) unsigned int u32x4;

__device__ __forceinline__ unsigned short f2bf(float f) {
  union { float f; unsigned int u; } c; c.f = f;
  unsigned int u = c.u;
  u += 0x7FFFu + ((u >> 16) & 1u);   // round-to-nearest-even
  return (unsigned short)(u >> 16);
}
__device__ __forceinline__ float bf2f(unsigned short b) {
  union { unsigned int u; float f; } c; c.u = ((unsigned int)b) << 16;
  return c.f;
}
__device__ __forceinline__ void acc8(const u32x4& v, float* a) {
  a[0] += bf2f((unsigned short)(v[0] & 0xFFFF)); a[1] += bf2f((unsigned short)(v[0] >> 16));
  a[2] += bf2f((unsigned short)(v[1] & 0xFFFF)); a[3] += bf2f((unsigned short)(v[1] >> 16));
  a[4] += bf2f((unsigned short)(v[2] & 0xFFFF)); a[5] += bf2f((unsigned short)(v[2] >> 16));
  a[6] += bf2f((unsigned short)(v[3] & 0xFFFF)); a[7] += bf2f((unsigned short)(v[3] >> 16));
}

// ---- convert two fp32 arrays to bf16 (blockIdx.y selects which) ----
__global__ void cvt_x(const float* __restrict__ a, const float* __restrict__ b,
                      unsigned short* __restrict__ oa, unsigned short* __restrict__ ob, int n) {
  const float* src = blockIdx.y ? b : a;
  unsigned short* dst = blockIdx.y ? ob : oa;
  int i = (blockIdx.x * 256 + threadIdx.x) * 8;
  if (i >= n) return;
  float4 v0 = *(const float4*)(src + i);
  float4 v1 = *(const float4*)(src + i + 4);
  u32x4 o;
  o[0] = (unsigned int)f2bf(v0.x) | ((unsigned int)f2bf(v0.y) << 16);
  o[1] = (unsigned int)f2bf(v0.z) | ((unsigned int)f2bf(v0.w) << 16);
  o[2] = (unsigned int)f2bf(v1.x) | ((unsigned int)f2bf(v1.y) << 16);
  o[3] = (unsigned int)f2bf(v1.z) | ((unsigned int)f2bf(v1.w) << 16);
  *(u32x4*)(dst + i) = o;
}

struct WPtrs { const float* p[8]; };

// ---- convert the 8 [128x128] weight matrices to bf16 ----
__global__ void cvt_w(WPtrs w, unsigned short* __restrict__ out) {
  int wi = blockIdx.y;
  int i = (blockIdx.x * 256 + threadIdx.x) * 8;
  const float* src = w.p[wi];
  float4 v0 = *(const float4*)(src + i);
  float4 v1 = *(const float4*)(src + i + 4);
  u32x4 o;
  o[0] = (unsigned int)f2bf(v0.x) | ((unsigned int)f2bf(v0.y) << 16);
  o[1] = (unsigned int)f2bf(v0.z) | ((unsigned int)f2bf(v0.w) << 16);
  o[2] = (unsigned int)f2bf(v1.x) | ((unsigned int)f2bf(v1.y) << 16);
  o[3] = (unsigned int)f2bf(v1.z) | ((unsigned int)f2bf(v1.w) << 16);
  *(u32x4*)(out + wi * 16384 + i) = o;
}

// ---- counting-sort pipeline, both relations per launch (blockIdx.y) ----
// hist/reorder: 4 edges per thread (int4 loads) -> 4 independent atomic chains
__global__ void hist2_k(const int* __restrict__ ei0, const int* __restrict__ ei1,
                        int* __restrict__ cnt, int E, int N) {
  const int* ei = blockIdx.y ? ei1 : ei0;
  int* c = cnt + blockIdx.y * N;
  int e = (blockIdx.x * 256 + threadIdx.x) * 4;
  if (e >= E) return;
  if (e + 4 <= E) {
    int4 d4 = *(const int4*)(ei + E + e);
    atomicAdd(&c[d4.x], 1); atomicAdd(&c[d4.y], 1);
    atomicAdd(&c[d4.z], 1); atomicAdd(&c[d4.w], 1);
  } else {
    for (int k = 0; k < 4 && e + k < E; ++k) atomicAdd(&c[ei[E + e + k]], 1);
  }
}

__global__ void scan_a2(const int* __restrict__ cnt, int* __restrict__ incl,
                        int* __restrict__ bsum, int n) {
  const int* in = cnt + blockIdx.y * n;
  int* out = incl + blockIdx.y * n;
  int* bs = bsum + blockIdx.y * 128;
  __shared__ int sm[1024];
  int i = blockIdx.x * 1024 + threadIdx.x;
  int v = (i < n) ? in[i] : 0;
  sm[threadIdx.x] = v;
  __syncthreads();
  for (int off = 1; off < 1024; off <<= 1) {
    int t = (threadIdx.x >= off) ? sm[threadIdx.x - off] : 0;
    __syncthreads();
    sm[threadIdx.x] += t;
    __syncthreads();
  }
  if (i < n) out[i] = sm[threadIdx.x];
  if (threadIdx.x == 1023) bs[blockIdx.x] = sm[1023];
}

__global__ void scan_b2(int* __restrict__ bsum, int nb) {
  int* bs = bsum + blockIdx.y * 128;
  __shared__ int sm[128];
  int t = threadIdx.x;
  int v = (t < nb) ? bs[t] : 0;
  sm[t] = v;
  __syncthreads();
  for (int off = 1; off < 128; off <<= 1) {
    int u = (t >= off) ? sm[t - off] : 0;
    __syncthreads();
    sm[t] += u;
    __syncthreads();
  }
  if (t < nb) bs[t] = sm[t] - v;   // exclusive block offsets
}

__global__ void scan_c2(const int* __restrict__ cnt, const int* __restrict__ incl,
                        const int* __restrict__ bsum, int* __restrict__ rowptr,
                        int* __restrict__ cursor, int n) {
  int y = blockIdx.y;
  int i = blockIdx.x * 256 + threadIdx.x;
  if (i >= n) return;
  int e = incl[y * n + i] - cnt[y * n + i] + bsum[y * 128 + (i >> 10)];
  rowptr[y * n + i] = e;
  cursor[y * n + i] = e;
}

__global__ void reorder2_k(const int* __restrict__ ei0, const int* __restrict__ ei1,
                           int* __restrict__ cursor, int* __restrict__ ssrc, int E, int N) {
  const int* ei = blockIdx.y ? ei1 : ei0;
  int* cur = cursor + blockIdx.y * N;
  int* ss = ssrc + blockIdx.y * E;
  int e = (blockIdx.x * 256 + threadIdx.x) * 4;
  if (e >= E) return;
  if (e + 4 <= E) {
    int4 s4 = *(const int4*)(ei + e);
    int4 d4 = *(const int4*)(ei + E + e);
    int p0 = atomicAdd(&cur[d4.x], 1);
    int p1 = atomicAdd(&cur[d4.y], 1);
    int p2 = atomicAdd(&cur[d4.z], 1);
    int p3 = atomicAdd(&cur[d4.w], 1);
    ss[p0] = s4.x; ss[p1] = s4.y; ss[p2] = s4.z; ss[p3] = s4.w;
  } else {
    for (int k = 0; k < 4 && e + k < E; ++k) {
      int s = ei[e + k], d = ei[E + e + k];
      ss[atomicAdd(&cur[d], 1)] = s;
    }
  }
}

// ---- fused gather-mean + dual matmul ----
// out = mean_csr(xsrc) @ Wl^T + xdst @ Wr^T + bias (+relu->bf16 | ->f32)
// Gather: NODE-parallel (round-6 lesson: LDS FP atomics = CAS-loop disaster),
// PAIRED sweeps -> 16 independent row loads in flight per lane (round-5's 8
// wasn't enough MLP). 16 lanes/node, bf16x8/lane.
struct FusedArgs {
  const unsigned short* xsrc; const unsigned short* xdst;
  const int* rowptr; const int* cnt; const int* ssrc;
  const unsigned short* Wl; const unsigned short* Wr;
  const float* bias; void* out;
};

template<int RELU_BF16>
__global__ __launch_bounds__(256, 4) void fused_k(FusedArgs f0, FusedArgs f1, int n) {
  FusedArgs A = blockIdx.y ? f1 : f0;
  __shared__ __align__(16) unsigned short lds[2 * 64 * 136];   // 34816 B
  int n0 = blockIdx.x * 64;
  int tid = threadIdx.x;
  int wave = tid >> 6, lane = tid & 63;
  int lr = lane & 15;             // A row-in-16 / B col-in-16
  int kb = (lane >> 4) * 8;       // k sub-offset within the 32-wide K step

  // ---- phase 1: gather-mean into lds[0]; 4 sweeps processed in 2 pairs ----
  {
    int g = tid >> 4;             // node-in-sweep
    int q = (tid & 15) * 8;       // bf16 column offset
    int begs[4], degs[4];
    #pragma unroll
    for (int s = 0; s < 4; ++s) {
      int nd = n0 + s * 16 + g;
      bool ok = nd < n;
      begs[s] = ok ? A.rowptr[nd] : 0;
      degs[s] = ok ? A.cnt[nd] : 0;
    }
    #pragma unroll
    for (int p = 0; p < 2; ++p) {
      int sA = 2 * p, sB = 2 * p + 1;
      int dA = degs[sA], dB = degs[sB];
      int bA = dA > 0 ? begs[sA] : 0, lA = dA > 0 ? begs[sA] + dA - 1 : 0;
      int bB = dB > 0 ? begs[sB] : 0, lB = dB > 0 ? begs[sB] + dB - 1 : 0;
      // 16 independent clamped index loads
      int iA[8], iB[8];
      #pragma unroll
      for (int j = 0; j < 8; ++j) iA[j] = A.ssrc[min(bA + j, lA)];
      #pragma unroll
      for (int j = 0; j < 8; ++j) iB[j] = A.ssrc[min(bB + j, lB)];
      // 16 independent row loads in flight
      u32x4 rA[8], rB[8];
      #pragma unroll
      for (int j = 0; j < 8; ++j) rA[j] = *(const u32x4*)(A.xsrc + (size_t)iA[j] * 128 + q);
      #pragma unroll
      for (int j = 0; j < 8; ++j) rB[j] = *(const u32x4*)(A.xsrc + (size_t)iB[j] * 128 + q);
      float aA[8] = {0.f,0.f,0.f,0.f,0.f,0.f,0.f,0.f};
      float aB[8] = {0.f,0.f,0.f,0.f,0.f,0.f,0.f,0.f};
      #pragma unroll
      for (int j = 0; j < 8; ++j) if (dA > j) acc8(rA[j], aA);
      #pragma unroll
      for (int j = 0; j < 8; ++j) if (dB > j) acc8(rB[j], aB);
      // rare tail (P(deg>8) ~ 0.15 at mean deg 6): batch-8 clamped again
      for (int t = 8; t < dA; t += 8) {
        int ii[8]; u32x4 rr[8];
        #pragma unroll
        for (int j = 0; j < 8; ++j) ii[j] = A.ssrc[min(bA + t + j, lA)];
        #pragma unroll
        for (int j = 0; j < 8; ++j) rr[j] = *(const u32x4*)(A.xsrc + (size_t)ii[j] * 128 + q);
        #pragma unroll
        for (int j = 0; j < 8; ++j) if (dA - t > j) acc8(rr[j], aA);
      }
      for (int t = 8; t < dB; t += 8) {
        int ii[8]; u32x4 rr[8];
        #pragma unroll
        for (int j = 0; j < 8; ++j) ii[j] = A.ssrc[min(bB + t + j, lB)];
        #pragma unroll
        for (int j = 0; j < 8; ++j) rr[j] = *(const u32x4*)(A.xsrc + (size_t)ii[j] * 128 + q);
        #pragma unroll
        for (int j = 0; j < 8; ++j) if (dB - t > j) acc8(rr[j], aB);
      }
      float invA = dA > 0 ? 1.0f / (float)dA : 0.0f;
      float invB = dB > 0 ? 1.0f / (float)dB : 0.0f;
      u32x4 oA, oB;
      oA[0] = (unsigned int)f2bf(aA[0]*invA) | ((unsigned int)f2bf(aA[1]*invA) << 16);
      oA[1] = (unsigned int)f2bf(aA[2]*invA) | ((unsigned int)f2bf(aA[3]*invA) << 16);
      oA[2] = (unsigned int)f2bf(aA[4]*invA) | ((unsigned int)f2bf(aA[5]*invA) << 16);
      oA[3] = (unsigned int)f2bf(aA[6]*invA) | ((unsigned int)f2bf(aA[7]*invA) << 16);
      oB[0] = (unsigned int)f2bf(aB[0]*invB) | ((unsigned int)f2bf(aB[1]*invB) << 16);
      oB[1] = (unsigned int)f2bf(aB[2]*invB) | ((unsigned int)f2bf(aB[3]*invB) << 16);
      oB[2] = (unsigned int)f2bf(aB[4]*invB) | ((unsigned int)f2bf(aB[5]*invB) << 16);
      oB[3] = (unsigned int)f2bf(aB[6]*invB) | ((unsigned int)f2bf(aB[7]*invB) << 16);
      *(u32x4*)(lds + (sA * 16 + g) * 136 + q) = oA;
      *(u32x4*)(lds + (sB * 16 + g) * 136 + q) = oB;
    }
  }

  // ---- phase 1b: copy xdst tile into lds[1] ----
  {
    unsigned short* dstl = lds + 64 * 136;
    #pragma unroll
    for (int it = 0; it < 4; ++it) {
      int li = (it * 256 + tid) * 8;
      int r = li >> 7, c = li & 127;
      u32x4 v = {0u, 0u, 0u, 0u};
      int row = n0 + r;
      if (row < n) v = *(const u32x4*)(A.xdst + (size_t)row * 128 + c);
      *(u32x4*)(dstl + r * 136 + c) = v;
    }
  }

  // ---- preload this wave's 16 B fragments (2 h x 2 jt x 4 ks) ----
  const unsigned short* Wg[2] = { A.Wl, A.Wr };
  bf16x8 breg[2][2][4];
  #pragma unroll
  for (int h = 0; h < 2; ++h) {
    const unsigned short* wb = Wg[h] + (size_t)(wave * 32 + lr) * 128 + kb;
    #pragma unroll
    for (int jt = 0; jt < 2; ++jt)
      #pragma unroll
      for (int ks = 0; ks < 4; ++ks)
        breg[h][jt][ks] = *(const bf16x8*)(wb + jt * 16 * 128 + ks * 32);
  }
  __syncthreads();

  // ---- pure LDS + register MFMA loop: 32 ds_read_b128, 64 MFMA ----
  f32x4 acc[4][2] = {};           // [row tile][col tile], statically indexed
  #pragma unroll
  for (int h = 0; h < 2; ++h) {
    const unsigned short* Abase = lds + h * 64 * 136 + lr * 136 + kb;
    #pragma unroll
    for (int rt = 0; rt < 4; ++rt) {
      #pragma unroll
      for (int ks = 0; ks < 4; ++ks) {
        bf16x8 a = *(const bf16x8*)(Abase + rt * 16 * 136 + ks * 32);
        acc[rt][0] = __builtin_amdgcn_mfma_f32_16x16x32_bf16(a, breg[h][0][ks], acc[rt][0], 0, 0, 0);
        acc[rt][1] = __builtin_amdgcn_mfma_f32_16x16x32_bf16(a, breg[h][1][ks], acc[rt][1], 0, 0, 0);
      }
    }
  }

  // ---- epilogue: acc -> LDS (overlay) -> coalesced full-row global stores ----
  // C/D layout: col = lane&15, row = (lane>>4)*4 + reg  [verified m89/m91]
  __syncthreads();                // all A-tile reads done; safe to overlay lds
  if (RELU_BF16) {
    unsigned short* st = (unsigned short*)lds;   // 64 x 128, stride 136
    #pragma unroll
    for (int jt = 0; jt < 2; ++jt) {
      int col = wave * 32 + jt * 16 + lr;
      float bv = A.bias[col];
      #pragma unroll
      for (int rt = 0; rt < 4; ++rt) {
        int rloc = rt * 16 + (lane >> 4) * 4;
        #pragma unroll
        for (int i = 0; i < 4; ++i) {
          float v = acc[rt][jt][i] + bv;
          v = v > 0.f ? v : 0.f;
          st[(rloc + i) * 136 + col] = f2bf(v);
        }
      }
    }
    __syncthreads();
    #pragma unroll
    for (int it = 0; it < 4; ++it) {
      int flat = (it * 256 + tid) * 8;
      int r = flat >> 7, c = flat & 127;
      if (n0 + r < n) {
        u32x4 v = *(const u32x4*)(st + r * 136 + c);
        *(u32x4*)((unsigned short*)A.out + (size_t)(n0 + r) * 128 + c) = v;
      }
    }
  } else {
    float* st = (float*)lds;                     // 64 x 128, stride 132
    #pragma unroll
    for (int jt = 0; jt < 2; ++jt) {
      int col = wave * 32 + jt * 16 + lr;
      float bv = A.bias[col];
      #pragma unroll
      for (int rt = 0; rt < 4; ++rt) {
        int rloc = rt * 16 + (lane >> 4) * 4;
        #pragma unroll
        for (int i = 0; i < 4; ++i)
          st[(rloc + i) * 132 + col] = acc[rt][jt][i] + bv;
      }
    }
    __syncthreads();
    #pragma unroll
    for (int it = 0; it < 8; ++it) {
      int flat = (it * 256 + tid) * 4;
      int r = flat >> 7, c = flat & 127;
      if (n0 + r < n) {
        u32x4 v = *(const u32x4*)(st + r * 132 + c);
        *(u32x4*)((float*)A.out + (size_t)(n0 + r) * 128 + c) = v;
      }
    }
  }
}

extern "C" void kernel_launch(void* const* d_in, const int* in_sizes, int n_in,
                              void* d_out, int out_size, void* d_ws, size_t ws_size,
                              hipStream_t stream) {
  const float* xp = (const float*)d_in[0];
  const float* xt = (const float*)d_in[1];
  const int* ei_pt = (const int*)d_in[2];
  const int* ei_tp = (const int*)d_in[3];
  WPtrs wp;
  for (int i = 0; i < 8; ++i) wp.p[i] = (const float*)d_in[4 + i];
  const float* bl0_pt = (const float*)d_in[12];
  const float* bl0_tp = (const float*)d_in[13];
  const float* bl1_pt = (const float*)d_in[14];
  const float* bl1_tp = (const float*)d_in[15];
  float* out = (float*)d_out;     // [o_player (N*128) | o_team (N*128)]

  const int N = in_sizes[0] / 128;
  const int E = in_sizes[2] / 2;
  const size_t NB = (size_t)N * 128 * 2;    // bf16 feature matrix bytes

  char* ws = (char*)d_ws;
  size_t off = 0;
  auto alloc = [&](size_t bytes) -> void* {
    off = (off + 255) & ~(size_t)255;
    void* p = ws + off; off += bytes; return p;
  };
  unsigned short* xp_bf  = (unsigned short*)alloc(NB);
  unsigned short* xt_bf  = (unsigned short*)alloc(NB);
  unsigned short* hp_bf  = (unsigned short*)alloc(NB);
  unsigned short* ht_bf  = (unsigned short*)alloc(NB);
  unsigned short* wbf    = (unsigned short*)alloc(8 * 16384 * 2);
  int* cnt    = (int*)alloc((size_t)2 * N * 4);
  int* rowptr = (int*)alloc((size_t)2 * N * 4);
  int* cursor = (int*)alloc((size_t)2 * N * 4);
  int* incl   = (int*)alloc((size_t)2 * N * 4);
  int* ssrc   = (int*)alloc((size_t)2 * E * 4);
  int* bsum   = (int*)alloc(2 * 128 * 4);

  const int nx = N * 128;
  // fp32 -> bf16 conversions
  cvt_x<<<dim3((nx / 8 + 255) / 256, 2), 256, 0, stream>>>(xp, xt, xp_bf, xt_bf, nx);
  cvt_w<<<dim3(8, 8), 256, 0, stream>>>(wp, wbf);

  // CSR build, both relations per launch (reused by both layers)
  const int SCB = (N + 1023) / 1024;
  const int EB4 = ((E + 3) / 4 + 255) / 256;
  hipMemsetAsync(cnt, 0, (size_t)2 * N * 4, stream);
  hist2_k<<<dim3(EB4, 2), 256, 0, stream>>>(ei_pt, ei_tp, cnt, E, N);
  scan_a2<<<dim3(SCB, 2), 1024, 0, stream>>>(cnt, incl, bsum, N);
  scan_b2<<<dim3(1, 2), 128, 0, stream>>>(bsum, SCB);
  scan_c2<<<dim3((N + 255) / 256, 2), 256, 0, stream>>>(cnt, incl, bsum, rowptr, cursor, N);
  reorder2_k<<<dim3(EB4, 2), 256, 0, stream>>>(ei_pt, ei_tp, cursor, ssrc, E, N);

  const int LNB = (N + 63) / 64;
  // relation 0 = pt (dst type team), relation 1 = tp (dst type player)
  // ---- layer 0 (relu, bf16 out) ----
  FusedArgs l0a = { xp_bf, xt_bf, rowptr,     cnt,     ssrc,     wbf + 0*16384, wbf + 1*16384, bl0_pt, ht_bf };
  FusedArgs l0b = { xt_bf, xp_bf, rowptr + N, cnt + N, ssrc + E, wbf + 2*16384, wbf + 3*16384, bl0_tp, hp_bf };
  fused_k<1><<<dim3(LNB, 2), 256, 0, stream>>>(l0a, l0b, N);
  // ---- layer 1 (f32 out) ----
  FusedArgs l1a = { hp_bf, ht_bf, rowptr,     cnt,     ssrc,     wbf + 4*16384, wbf + 5*16384, bl1_pt, out + (size_t)N * 128 };
  FusedArgs l1b = { ht_bf, hp_bf, rowptr + N, cnt + N, ssrc + E, wbf + 6*16384, wbf + 7*16384, bl1_tp, out };
  fused_k<0><<<dim3(LNB, 2), 256, 0, stream>>>(l1a, l1b, N);
}

// Round 8
// 470.595 us; speedup vs baseline: 4.3345x; 1.0708x over previous
//
#include <hip/hip_runtime.h>
#include <hip/hip_bf16.h>
#include <stdint.h>

typedef __attribute__((ext_vector_type(8))) short bf16x8;
typedef __attribute__((ext_vector_type(4))) float f32x4;
typedef __attribute__((ext_vector_type(4))) unsigned int u32x4;

__device__ __forceinline__ unsigned short f2bf(float f) {
  union { float f; unsigned int u; } c; c.f = f;
  unsigned int u = c.u;
  u += 0x7FFFu + ((u >> 16) & 1u);   // round-to-nearest-even
  return (unsigned short)(u >> 16);
}
__device__ __forceinline__ float bf2f(unsigned short b) {
  union { unsigned int u; float f; } c; c.u = ((unsigned int)b) << 16;
  return c.f;
}
__device__ __forceinline__ void acc8(const u32x4& v, float* a) {
  a[0] += bf2f((unsigned short)(v[0] & 0xFFFF)); a[1] += bf2f((unsigned short)(v[0] >> 16));
  a[2] += bf2f((unsigned short)(v[1] & 0xFFFF)); a[3] += bf2f((unsigned short)(v[1] >> 16));
  a[4] += bf2f((unsigned short)(v[2] & 0xFFFF)); a[5] += bf2f((unsigned short)(v[2] >> 16));
  a[6] += bf2f((unsigned short)(v[3] & 0xFFFF)); a[7] += bf2f((unsigned short)(v[3] >> 16));
}

// ---- convert two fp32 arrays to bf16 (blockIdx.y selects which) ----
__global__ void cvt_x(const float* __restrict__ a, const float* __restrict__ b,
                      unsigned short* __restrict__ oa, unsigned short* __restrict__ ob, int n) {
  const float* src = blockIdx.y ? b : a;
  unsigned short* dst = blockIdx.y ? ob : oa;
  int i = (blockIdx.x * 256 + threadIdx.x) * 8;
  if (i >= n) return;
  float4 v0 = *(const float4*)(src + i);
  float4 v1 = *(const float4*)(src + i + 4);
  u32x4 o;
  o[0] = (unsigned int)f2bf(v0.x) | ((unsigned int)f2bf(v0.y) << 16);
  o[1] = (unsigned int)f2bf(v0.z) | ((unsigned int)f2bf(v0.w) << 16);
  o[2] = (unsigned int)f2bf(v1.x) | ((unsigned int)f2bf(v1.y) << 16);
  o[3] = (unsigned int)f2bf(v1.z) | ((unsigned int)f2bf(v1.w) << 16);
  *(u32x4*)(dst + i) = o;
}

struct WPtrs { const float* p[8]; };

// ---- convert the 8 [128x128] weight matrices to bf16 ----
__global__ void cvt_w(WPtrs w, unsigned short* __restrict__ out) {
  int wi = blockIdx.y;
  int i = (blockIdx.x * 256 + threadIdx.x) * 8;
  const float* src = w.p[wi];
  float4 v0 = *(const float4*)(src + i);
  float4 v1 = *(const float4*)(src + i + 4);
  u32x4 o;
  o[0] = (unsigned int)f2bf(v0.x) | ((unsigned int)f2bf(v0.y) << 16);
  o[1] = (unsigned int)f2bf(v0.z) | ((unsigned int)f2bf(v0.w) << 16);
  o[2] = (unsigned int)f2bf(v1.x) | ((unsigned int)f2bf(v1.y) << 16);
  o[3] = (unsigned int)f2bf(v1.z) | ((unsigned int)f2bf(v1.w) << 16);
  *(u32x4*)(out + wi * 16384 + i) = o;
}

// ---- counting-sort pipeline, both relations per launch (blockIdx.y) ----
__global__ void hist2_k(const int* __restrict__ ei0, const int* __restrict__ ei1,
                        int* __restrict__ cnt, int E, int N) {
  const int* ei = blockIdx.y ? ei1 : ei0;
  int* c = cnt + blockIdx.y * N;
  int e = (blockIdx.x * 256 + threadIdx.x) * 4;
  if (e >= E) return;
  if (e + 4 <= E) {
    int4 d4 = *(const int4*)(ei + E + e);
    atomicAdd(&c[d4.x], 1); atomicAdd(&c[d4.y], 1);
    atomicAdd(&c[d4.z], 1); atomicAdd(&c[d4.w], 1);
  } else {
    for (int k = 0; k < 4 && e + k < E; ++k) atomicAdd(&c[ei[E + e + k]], 1);
  }
}

__global__ void scan_a2(const int* __restrict__ cnt, int* __restrict__ incl,
                        int* __restrict__ bsum, int n) {
  const int* in = cnt + blockIdx.y * n;
  int* out = incl + blockIdx.y * n;
  int* bs = bsum + blockIdx.y * 128;
  __shared__ int sm[1024];
  int i = blockIdx.x * 1024 + threadIdx.x;
  int v = (i < n) ? in[i] : 0;
  sm[threadIdx.x] = v;
  __syncthreads();
  for (int off = 1; off < 1024; off <<= 1) {
    int t = (threadIdx.x >= off) ? sm[threadIdx.x - off] : 0;
    __syncthreads();
    sm[threadIdx.x] += t;
    __syncthreads();
  }
  if (i < n) out[i] = sm[threadIdx.x];
  if (threadIdx.x == 1023) bs[blockIdx.x] = sm[1023];
}

__global__ void scan_b2(int* __restrict__ bsum, int nb) {
  int* bs = bsum + blockIdx.y * 128;
  __shared__ int sm[128];
  int t = threadIdx.x;
  int v = (t < nb) ? bs[t] : 0;
  sm[t] = v;
  __syncthreads();
  for (int off = 1; off < 128; off <<= 1) {
    int u = (t >= off) ? sm[t - off] : 0;
    __syncthreads();
    sm[t] += u;
    __syncthreads();
  }
  if (t < nb) bs[t] = sm[t] - v;   // exclusive block offsets
}

__global__ void scan_c2(const int* __restrict__ cnt, const int* __restrict__ incl,
                        const int* __restrict__ bsum, int* __restrict__ rowptr,
                        int* __restrict__ cursor, int n) {
  int y = blockIdx.y;
  int i = blockIdx.x * 256 + threadIdx.x;
  if (i >= n) return;
  int e = incl[y * n + i] - cnt[y * n + i] + bsum[y * 128 + (i >> 10)];
  rowptr[y * n + i] = e;
  cursor[y * n + i] = e;
}

// ---- reorder with dst-range filtering for XCD-local scatter writes ----
// Round-7 lesson: scattered 4B stores cost a full 64B HBM line each (WRITE 77MB
// for 4.8MB payload) -> random-write BW ceiling. Fix: 8 dst-range groups, group
// g = blockIdx.x & 7 (empirically XCD = bid%8); group g handles only dst in
// [gN/8,(g+1)N/8), so its CSR writes span a 300KB window that stays resident in
// ONE XCD's L2 and lines accumulate ~16 stores before writeback. Cost: 8x
// re-read of the dst row (L2/L3-resident, coalesced int4).
__global__ void reorder3_k(const int* __restrict__ ei0, const int* __restrict__ ei1,
                           int* __restrict__ cursor, int* __restrict__ ssrc, int E, int N) {
  const int* ei = blockIdx.y ? ei1 : ei0;
  int* cur = cursor + blockIdx.y * N;
  int* ss = ssrc + blockIdx.y * E;
  int g = blockIdx.x & 7;
  int chunk = blockIdx.x >> 3;
  int lo = (int)(((long long)N * g) >> 3);
  int hi = (int)(((long long)N * (g + 1)) >> 3);
  int e = (chunk * 256 + threadIdx.x) * 4;
  if (e >= E) return;
  if (e + 4 <= E) {
    int4 d4 = *(const int4*)(ei + E + e);
    int4 s4 = *(const int4*)(ei + e);
    if (d4.x >= lo && d4.x < hi) ss[atomicAdd(&cur[d4.x], 1)] = s4.x;
    if (d4.y >= lo && d4.y < hi) ss[atomicAdd(&cur[d4.y], 1)] = s4.y;
    if (d4.z >= lo && d4.z < hi) ss[atomicAdd(&cur[d4.z], 1)] = s4.z;
    if (d4.w >= lo && d4.w < hi) ss[atomicAdd(&cur[d4.w], 1)] = s4.w;
  } else {
    for (int k = 0; k < 4 && e + k < E; ++k) {
      int d = ei[E + e + k];
      if (d >= lo && d < hi) ss[atomicAdd(&cur[d], 1)] = ei[e + k];
    }
  }
}

// ---- fused gather-mean + dual matmul ----
// out = mean_csr(xsrc) @ Wl^T + xdst @ Wr^T + bias (+relu->bf16 | ->f32)
struct FusedArgs {
  const unsigned short* xsrc; const unsigned short* xdst;
  const int* rowptr; const int* cnt; const int* ssrc;
  const unsigned short* Wl; const unsigned short* Wr;
  const float* bias; void* out;
};

template<int RELU_BF16>
__global__ __launch_bounds__(256, 4) void fused_k(FusedArgs f0, FusedArgs f1, int n) {
  FusedArgs A = blockIdx.y ? f1 : f0;
  __shared__ __align__(16) unsigned short lds[2 * 64 * 136];   // 34816 B
  int n0 = blockIdx.x * 64;
  int tid = threadIdx.x;
  int wave = tid >> 6, lane = tid & 63;
  int lr = lane & 15;             // A row-in-16 / B col-in-16
  int kb = (lane >> 4) * 8;       // k sub-offset within the 32-wide K step

  // ---- phase 1: gather-mean into lds[0]; 4 sweeps processed in 2 pairs ----
  {
    int g = tid >> 4;             // node-in-sweep
    int q = (tid & 15) * 8;       // bf16 column offset
    int begs[4], degs[4];
    #pragma unroll
    for (int s = 0; s < 4; ++s) {
      int nd = n0 + s * 16 + g;
      bool ok = nd < n;
      begs[s] = ok ? A.rowptr[nd] : 0;
      degs[s] = ok ? A.cnt[nd] : 0;
    }
    #pragma unroll
    for (int p = 0; p < 2; ++p) {
      int sA = 2 * p, sB = 2 * p + 1;
      int dA = degs[sA], dB = degs[sB];
      int bA = dA > 0 ? begs[sA] : 0, lA = dA > 0 ? begs[sA] + dA - 1 : 0;
      int bB = dB > 0 ? begs[sB] : 0, lB = dB > 0 ? begs[sB] + dB - 1 : 0;
      int iA[8], iB[8];
      #pragma unroll
      for (int j = 0; j < 8; ++j) iA[j] = A.ssrc[min(bA + j, lA)];
      #pragma unroll
      for (int j = 0; j < 8; ++j) iB[j] = A.ssrc[min(bB + j, lB)];
      u32x4 rA[8], rB[8];
      #pragma unroll
      for (int j = 0; j < 8; ++j) rA[j] = *(const u32x4*)(A.xsrc + (size_t)iA[j] * 128 + q);
      #pragma unroll
      for (int j = 0; j < 8; ++j) rB[j] = *(const u32x4*)(A.xsrc + (size_t)iB[j] * 128 + q);
      float aA[8] = {0.f,0.f,0.f,0.f,0.f,0.f,0.f,0.f};
      float aB[8] = {0.f,0.f,0.f,0.f,0.f,0.f,0.f,0.f};
      #pragma unroll
      for (int j = 0; j < 8; ++j) if (dA > j) acc8(rA[j], aA);
      #pragma unroll
      for (int j = 0; j < 8; ++j) if (dB > j) acc8(rB[j], aB);
      for (int t = 8; t < dA; t += 8) {
        int ii[8]; u32x4 rr[8];
        #pragma unroll
        for (int j = 0; j < 8; ++j) ii[j] = A.ssrc[min(bA + t + j, lA)];
        #pragma unroll
        for (int j = 0; j < 8; ++j) rr[j] = *(const u32x4*)(A.xsrc + (size_t)ii[j] * 128 + q);
        #pragma unroll
        for (int j = 0; j < 8; ++j) if (dA - t > j) acc8(rr[j], aA);
      }
      for (int t = 8; t < dB; t += 8) {
        int ii[8]; u32x4 rr[8];
        #pragma unroll
        for (int j = 0; j < 8; ++j) ii[j] = A.ssrc[min(bB + t + j, lB)];
        #pragma unroll
        for (int j = 0; j < 8; ++j) rr[j] = *(const u32x4*)(A.xsrc + (size_t)ii[j] * 128 + q);
        #pragma unroll
        for (int j = 0; j < 8; ++j) if (dB - t > j) acc8(rr[j], aB);
      }
      float invA = dA > 0 ? 1.0f / (float)dA : 0.0f;
      float invB = dB > 0 ? 1.0f / (float)dB : 0.0f;
      u32x4 oA, oB;
      oA[0] = (unsigned int)f2bf(aA[0]*invA) | ((unsigned int)f2bf(aA[1]*invA) << 16);
      oA[1] = (unsigned int)f2bf(aA[2]*invA) | ((unsigned int)f2bf(aA[3]*invA) << 16);
      oA[2] = (unsigned int)f2bf(aA[4]*invA) | ((unsigned int)f2bf(aA[5]*invA) << 16);
      oA[3] = (unsigned int)f2bf(aA[6]*invA) | ((unsigned int)f2bf(aA[7]*invA) << 16);
      oB[0] = (unsigned int)f2bf(aB[0]*invB) | ((unsigned int)f2bf(aB[1]*invB) << 16);
      oB[1] = (unsigned int)f2bf(aB[2]*invB) | ((unsigned int)f2bf(aB[3]*invB) << 16);
      oB[2] = (unsigned int)f2bf(aB[4]*invB) | ((unsigned int)f2bf(aB[5]*invB) << 16);
      oB[3] = (unsigned int)f2bf(aB[6]*invB) | ((unsigned int)f2bf(aB[7]*invB) << 16);
      *(u32x4*)(lds + (sA * 16 + g) * 136 + q) = oA;
      *(u32x4*)(lds + (sB * 16 + g) * 136 + q) = oB;
    }
  }

  // ---- phase 1b: copy xdst tile into lds[1] ----
  {
    unsigned short* dstl = lds + 64 * 136;
    #pragma unroll
    for (int it = 0; it < 4; ++it) {
      int li = (it * 256 + tid) * 8;
      int r = li >> 7, c = li & 127;
      u32x4 v = {0u, 0u, 0u, 0u};
      int row = n0 + r;
      if (row < n) v = *(const u32x4*)(A.xdst + (size_t)row * 128 + c);
      *(u32x4*)(dstl + r * 136 + c) = v;
    }
  }

  // ---- preload this wave's 16 B fragments (2 h x 2 jt x 4 ks) ----
  const unsigned short* Wg[2] = { A.Wl, A.Wr };
  bf16x8 breg[2][2][4];
  #pragma unroll
  for (int h = 0; h < 2; ++h) {
    const unsigned short* wb = Wg[h] + (size_t)(wave * 32 + lr) * 128 + kb;
    #pragma unroll
    for (int jt = 0; jt < 2; ++jt)
      #pragma unroll
      for (int ks = 0; ks < 4; ++ks)
        breg[h][jt][ks] = *(const bf16x8*)(wb + jt * 16 * 128 + ks * 32);
  }
  __syncthreads();

  // ---- pure LDS + register MFMA loop: 32 ds_read_b128, 64 MFMA ----
  f32x4 acc[4][2] = {};           // [row tile][col tile], statically indexed
  #pragma unroll
  for (int h = 0; h < 2; ++h) {
    const unsigned short* Abase = lds + h * 64 * 136 + lr * 136 + kb;
    #pragma unroll
    for (int rt = 0; rt < 4; ++rt) {
      #pragma unroll
      for (int ks = 0; ks < 4; ++ks) {
        bf16x8 a = *(const bf16x8*)(Abase + rt * 16 * 136 + ks * 32);
        acc[rt][0] = __builtin_amdgcn_mfma_f32_16x16x32_bf16(a, breg[h][0][ks], acc[rt][0], 0, 0, 0);
        acc[rt][1] = __builtin_amdgcn_mfma_f32_16x16x32_bf16(a, breg[h][1][ks], acc[rt][1], 0, 0, 0);
      }
    }
  }

  // ---- epilogue: acc -> LDS (overlay) -> coalesced full-row global stores ----
  // C/D layout: col = lane&15, row = (lane>>4)*4 + reg  [verified m89/m91]
  __syncthreads();                // all A-tile reads done; safe to overlay lds
  if (RELU_BF16) {
    unsigned short* st = (unsigned short*)lds;   // 64 x 128, stride 136
    #pragma unroll
    for (int jt = 0; jt < 2; ++jt) {
      int col = wave * 32 + jt * 16 + lr;
      float bv = A.bias[col];
      #pragma unroll
      for (int rt = 0; rt < 4; ++rt) {
        int rloc = rt * 16 + (lane >> 4) * 4;
        #pragma unroll
        for (int i = 0; i < 4; ++i) {
          float v = acc[rt][jt][i] + bv;
          v = v > 0.f ? v : 0.f;
          st[(rloc + i) * 136 + col] = f2bf(v);
        }
      }
    }
    __syncthreads();
    #pragma unroll
    for (int it = 0; it < 4; ++it) {
      int flat = (it * 256 + tid) * 8;
      int r = flat >> 7, c = flat & 127;
      if (n0 + r < n) {
        u32x4 v = *(const u32x4*)(st + r * 136 + c);
        *(u32x4*)((unsigned short*)A.out + (size_t)(n0 + r) * 128 + c) = v;
      }
    }
  } else {
    float* st = (float*)lds;                     // 64 x 128, stride 132
    #pragma unroll
    for (int jt = 0; jt < 2; ++jt) {
      int col = wave * 32 + jt * 16 + lr;
      float bv = A.bias[col];
      #pragma unroll
      for (int rt = 0; rt < 4; ++rt) {
        int rloc = rt * 16 + (lane >> 4) * 4;
        #pragma unroll
        for (int i = 0; i < 4; ++i)
          st[(rloc + i) * 132 + col] = acc[rt][jt][i] + bv;
      }
    }
    __syncthreads();
    #pragma unroll
    for (int it = 0; it < 8; ++it) {
      int flat = (it * 256 + tid) * 4;
      int r = flat >> 7, c = flat & 127;
      if (n0 + r < n) {
        u32x4 v = *(const u32x4*)(st + r * 132 + c);
        *(u32x4*)((float*)A.out + (size_t)(n0 + r) * 128 + c) = v;
      }
    }
  }
}

extern "C" void kernel_launch(void* const* d_in, const int* in_sizes, int n_in,
                              void* d_out, int out_size, void* d_ws, size_t ws_size,
                              hipStream_t stream) {
  const float* xp = (const float*)d_in[0];
  const float* xt = (const float*)d_in[1];
  const int* ei_pt = (const int*)d_in[2];
  const int* ei_tp = (const int*)d_in[3];
  WPtrs wp;
  for (int i = 0; i < 8; ++i) wp.p[i] = (const float*)d_in[4 + i];
  const float* bl0_pt = (const float*)d_in[12];
  const float* bl0_tp = (const float*)d_in[13];
  const float* bl1_pt = (const float*)d_in[14];
  const float* bl1_tp = (const float*)d_in[15];
  float* out = (float*)d_out;     // [o_player (N*128) | o_team (N*128)]

  const int N = in_sizes[0] / 128;
  const int E = in_sizes[2] / 2;
  const size_t NB = (size_t)N * 128 * 2;    // bf16 feature matrix bytes

  char* ws = (char*)d_ws;
  size_t off = 0;
  auto alloc = [&](size_t bytes) -> void* {
    off = (off + 255) & ~(size_t)255;
    void* p = ws + off; off += bytes; return p;
  };
  unsigned short* xp_bf  = (unsigned short*)alloc(NB);
  unsigned short* xt_bf  = (unsigned short*)alloc(NB);
  unsigned short* hp_bf  = (unsigned short*)alloc(NB);
  unsigned short* ht_bf  = (unsigned short*)alloc(NB);
  unsigned short* wbf    = (unsigned short*)alloc(8 * 16384 * 2);
  int* cnt    = (int*)alloc((size_t)2 * N * 4);
  int* rowptr = (int*)alloc((size_t)2 * N * 4);
  int* cursor = (int*)alloc((size_t)2 * N * 4);
  int* incl   = (int*)alloc((size_t)2 * N * 4);
  int* ssrc   = (int*)alloc((size_t)2 * E * 4);
  int* bsum   = (int*)alloc(2 * 128 * 4);

  const int nx = N * 128;
  // fp32 -> bf16 conversions
  cvt_x<<<dim3((nx / 8 + 255) / 256, 2), 256, 0, stream>>>(xp, xt, xp_bf, xt_bf, nx);
  cvt_w<<<dim3(8, 8), 256, 0, stream>>>(wp, wbf);

  // CSR build, both relations per launch (reused by both layers)
  const int SCB = (N + 1023) / 1024;
  const int EB4 = ((E + 3) / 4 + 255) / 256;
  hipMemsetAsync(cnt, 0, (size_t)2 * N * 4, stream);
  hist2_k<<<dim3(EB4, 2), 256, 0, stream>>>(ei_pt, ei_tp, cnt, E, N);
  scan_a2<<<dim3(SCB, 2), 1024, 0, stream>>>(cnt, incl, bsum, N);
  scan_b2<<<dim3(1, 2), 128, 0, stream>>>(bsum, SCB);
  scan_c2<<<dim3((N + 255) / 256, 2), 256, 0, stream>>>(cnt, incl, bsum, rowptr, cursor, N);
  reorder3_k<<<dim3(EB4 * 8, 2), 256, 0, stream>>>(ei_pt, ei_tp, cursor, ssrc, E, N);

  const int LNB = (N + 63) / 64;
  // relation 0 = pt (dst type team), relation 1 = tp (dst type player)
  // ---- layer 0 (relu, bf16 out) ----
  FusedArgs l0a = { xp_bf, xt_bf, rowptr,     cnt,     ssrc,     wbf + 0*16384, wbf + 1*16384, bl0_pt, ht_bf };
  FusedArgs l0b = { xt_bf, xp_bf, rowptr + N, cnt + N, ssrc + E, wbf + 2*16384, wbf + 3*16384, bl0_tp, hp_bf };
  fused_k<1><<<dim3(LNB, 2), 256, 0, stream>>>(l0a, l0b, N);
  // ---- layer 1 (f32 out) ----
  FusedArgs l1a = { hp_bf, ht_bf, rowptr,     cnt,     ssrc,     wbf + 4*16384, wbf + 5*16384, bl1_pt, out + (size_t)N * 128 };
  FusedArgs l1b = { ht_bf, hp_bf, rowptr + N, cnt + N, ssrc + E, wbf + 6*16384, wbf + 7*16384, bl1_tp, out };
  fused_k<0><<<dim3(LNB, 2), 256, 0, stream>>>(l1a, l1b, N);
}